// Round 1
// baseline (465.819 us; speedup 1.0000x reference)
//
#include <hip/hip_runtime.h>
#include <cmath>

#define NBINS   84
#define NFRAMES 256
#define HOP     1024
#define NB      8     // nb_samples * nb_channels = 4*2

struct CqtArgs {
    int   wl[NBINS];     // per-bin window length (ragged)
    int   off[NBINS];    // prefix-sum offsets into basis table
    float omega[NBINS];  // radians per sample: 2*pi*f/SR
    float invL[NBINS];   // 1.0 / wl
};

// Build the fused basis table: basis[off_k + t] = (cos(w t)*win, sin(w t)*win, win^2, 0)
// win = periodic Hann: 0.5 - 0.5*cos(2*pi*t/L)
__global__ void build_basis(float4* __restrict__ basis, CqtArgs a) {
    const int k    = blockIdx.x;
    const int L    = a.wl[k];
    const int off  = a.off[k];
    const float om = a.omega[k];
    const float iL = a.invL[k];
    const float TWOPI = 6.28318530717958647692f;
    for (int t = threadIdx.x; t < L; t += blockDim.x) {
        float tf  = (float)t;
        float ang = om * tf;
        float s = sinf(ang);
        float c = cosf(ang);
        float w = 0.5f - 0.5f * cosf(TWOPI * tf * iL);
        basis[off + t] = make_float4(c * w, s * w, w * w, 0.0f);
    }
}

// Gather: one thread per output sample p; accumulates all 8 batches + norm.
// Contribution of (k, f): t = p - f*HOP, valid iff 0 <= t < L_k.
//   out[b][p] += Re(c[b,k,f]) * cos(w t) * win - Im(c[b,k,f]) * sin(w t) * win
//   norm[p]   += win^2
template<bool USE_TABLE>
__global__ void icqt_gather(const float* __restrict__ X, float* __restrict__ out,
                            const float4* __restrict__ basis, CqtArgs a, int length) {
    const int p = blockIdx.x * blockDim.x + threadIdx.x;
    if (p >= length) return;

    float acc[NB];
#pragma unroll
    for (int b = 0; b < NB; ++b) acc[b] = 0.0f;
    float nrm = 0.0f;

    int fhi = p >> 10;                      // t >= 0
    if (fhi > NFRAMES - 1) fhi = NFRAMES - 1;

    const float2* X2 = reinterpret_cast<const float2*>(X);

    for (int k = 0; k < NBINS; ++k) {
        const int L   = a.wl[k];
        const int off = a.off[k];
        int flo = (p - L + HOP) >> 10;      // ceil((p - L + 1)/1024); arith shift floors
        if (flo < 0) flo = 0;

        for (int f = flo; f <= fhi; ++f) {
            const int t = p - (f << 10);
            float bre, bim, w2;
            if (USE_TABLE) {
                float4 bs = basis[off + t];
                bre = bs.x; bim = bs.y; w2 = bs.z;
            } else {
                float tf  = (float)t;
                float ang = a.omega[k] * tf;
                float s = sinf(ang), c = cosf(ang);
                float w = 0.5f - 0.5f * cosf(6.28318530717958647692f * tf * a.invL[k]);
                bre = c * w; bim = s * w; w2 = w * w;
            }
            nrm += w2;
            const int base = (k * NFRAMES + f);   // per-batch stride below
#pragma unroll
            for (int b = 0; b < NB; ++b) {
                float2 cv = X2[(size_t)b * (NBINS * NFRAMES) + base];
                acc[b] += cv.x * bre - cv.y * bim;
            }
        }
    }

    const float n   = (nrm > 1e-10f) ? nrm : 1.0f;
    const float inv = 1.0f / n;
#pragma unroll
    for (int b = 0; b < NB; ++b)
        out[(size_t)b * length + p] = acc[b] * inv;
}

extern "C" void kernel_launch(void* const* d_in, const int* in_sizes, int n_in,
                              void* d_out, int out_size, void* d_ws, size_t ws_size,
                              hipStream_t stream) {
    // Static CQT geometry, computed fresh each call (deterministic, host-only math).
    CqtArgs a;
    const double SR = 44100.0;
    const double Q  = 1.0 / (std::exp2(1.0 / 12.0) - 1.0);
    int sum = 0;
    for (int k = 0; k < NBINS; ++k) {
        double f = 32.7 * std::exp2((double)k / 12.0);
        int L = (int)std::nearbyint(Q * SR / f);   // round-half-even == np.round
        a.wl[k]    = L;
        a.off[k]   = sum;
        a.omega[k] = (float)(2.0 * 3.14159265358979323846 * f / SR);
        a.invL[k]  = (float)(1.0 / (double)L);
        sum += L;
    }

    const int length = out_size / NB;             // (256-1)*1024 + wl[0] = 283800
    const float* X = (const float*)d_in[0];
    float* out     = (float*)d_out;

    const size_t need = (size_t)sum * sizeof(float4);
    const int threads = 256;
    const int blocks  = (length + threads - 1) / threads;

    if (ws_size >= need) {
        build_basis<<<NBINS, 256, 0, stream>>>((float4*)d_ws, a);
        icqt_gather<true><<<blocks, threads, 0, stream>>>(X, out, (const float4*)d_ws, a, length);
    } else {
        icqt_gather<false><<<blocks, threads, 0, stream>>>(X, out, nullptr, a, length);
    }
}

// Round 2
// 196.407 us; speedup vs baseline: 2.3717x; 2.3717x over previous
//
#include <hip/hip_runtime.h>
#include <hip/hip_fp16.h>
#include <cmath>

#define NBINS   84
#define NFRAMES 256
#define HOP     1024
#define NB      8     // nb_samples * nb_channels = 4*2
#define BPT     4     // batches per thread (2-way split for occupancy)

struct CqtArgs {
    int   wl[NBINS];     // per-bin window length (ragged)
    int   off[NBINS];    // prefix-sum offsets into basis table
    float omega[NBINS];  // radians per sample: 2*pi*f/SR
    float invL[NBINS];   // 1.0 / wl
};

// basis[off_k + t] = half2(cos(w t)*win, sin(w t)*win); win^2 recovered as x^2+y^2
__global__ void build_basis_h2(__half2* __restrict__ basis, CqtArgs a) {
    const int k = blockIdx.x;
    const int L = a.wl[k];
    const int t = blockIdx.y * blockDim.x + threadIdx.x;
    if (t >= L) return;
    const float TWOPI = 6.28318530717958647692f;
    const float tf  = (float)t;
    const float ang = a.omega[k] * tf;
    const float w   = 0.5f - 0.5f * cosf(TWOPI * tf * a.invL[k]);
    basis[a.off[k] + t] = __floats2half2_rn(cosf(ang) * w, sinf(ang) * w);
}

// Xt[(k*256+f)*8 + b] = X[b*(84*256) + k*256 + f]   (complex float2 entries)
__global__ void transpose_x(const float2* __restrict__ X2, float2* __restrict__ Xt2) {
    const int gid = blockIdx.x * blockDim.x + threadIdx.x;
    if (gid >= NBINS * NFRAMES * NB) return;
    const int kf = gid >> 3;
    const int b  = gid & 7;
    Xt2[gid] = X2[b * (NBINS * NFRAMES) + kf];
}

// One thread per (output position, batch-half). 4 batch accumulators + norm.
__global__ __launch_bounds__(256)
void icqt_gather2(const float4* __restrict__ Xt4, float* __restrict__ out,
                  const __half2* __restrict__ basis, CqtArgs a,
                  int length, int blocksPerHalf) {
    const int g = (blockIdx.x >= blocksPerHalf) ? 1 : 0;
    const int p = (blockIdx.x - g * blocksPerHalf) * blockDim.x + threadIdx.x;
    if (p >= length) return;

    float a0 = 0.f, a1 = 0.f, a2 = 0.f, a3 = 0.f, nrm = 0.f;

    int fhi = p >> 10;                    // wave-uniform (64 | 1024, waves aligned)
    if (fhi > NFRAMES - 1) fhi = NFRAMES - 1;

    for (int k = 0; k < NBINS; ++k) {
        const int L   = a.wl[k];
        const int off = a.off[k];
        int flo = (p - L + HOP) >> 10;    // arith shift floors; may be negative
        flo = __builtin_amdgcn_readfirstlane(flo);   // min over wave = lane 0
        if (flo < 0) flo = 0;

        // per-kf group: 8 float2 = 4 float4; half g owns float4 slots {g*2, g*2+1}
        const float4* xp = Xt4 + ((size_t)(k * NFRAMES + flo) * 4 + g * 2);
        for (int f = flo; f <= fhi; ++f, xp += 4) {
            const int  t     = p - (f << 10);
            const bool valid = (t < L);               // t >= 0 guaranteed
            float2 bf = __half22float2(basis[off + t]); // may over-read into pad: selected away
            const float bre = valid ? bf.x : 0.0f;    // cndmask (no NaN*0 hazard)
            const float bim = valid ? bf.y : 0.0f;
            const float4 q0 = xp[0];
            const float4 q1 = xp[1];
            a0  += q0.x * bre - q0.y * bim;
            a1  += q0.z * bre - q0.w * bim;
            a2  += q1.x * bre - q1.y * bim;
            a3  += q1.z * bre - q1.w * bim;
            nrm += bre * bre + bim * bim;             // = win^2 (selected lanes)
        }
    }

    const float inv = 1.0f / ((nrm > 1e-10f) ? nrm : 1.0f);
    float* o = out + (size_t)(g * BPT) * length + p;
    o[0]                  = a0 * inv;
    o[(size_t)length]     = a1 * inv;
    o[(size_t)length * 2] = a2 * inv;
    o[(size_t)length * 3] = a3 * inv;
}

// Fallback (ws too small): round-1 style on-the-fly trig, all 8 batches/thread.
__global__ void icqt_gather_fallback(const float* __restrict__ X, float* __restrict__ out,
                                     CqtArgs a, int length) {
    const int p = blockIdx.x * blockDim.x + threadIdx.x;
    if (p >= length) return;
    float acc[NB];
#pragma unroll
    for (int b = 0; b < NB; ++b) acc[b] = 0.0f;
    float nrm = 0.0f;
    int fhi = p >> 10;
    if (fhi > NFRAMES - 1) fhi = NFRAMES - 1;
    const float2* X2 = reinterpret_cast<const float2*>(X);
    for (int k = 0; k < NBINS; ++k) {
        const int L = a.wl[k];
        int flo = (p - L + HOP) >> 10;
        if (flo < 0) flo = 0;
        for (int f = flo; f <= fhi; ++f) {
            const int t = p - (f << 10);
            if (t < L) {
                float tf = (float)t;
                float ang = a.omega[k] * tf;
                float s = sinf(ang), c = cosf(ang);
                float w = 0.5f - 0.5f * cosf(6.28318530717958647692f * tf * a.invL[k]);
                float bre = c * w, bim = s * w;
                nrm += w * w;
                const int base = k * NFRAMES + f;
#pragma unroll
                for (int b = 0; b < NB; ++b) {
                    float2 cv = X2[(size_t)b * (NBINS * NFRAMES) + base];
                    acc[b] += cv.x * bre - cv.y * bim;
                }
            }
        }
    }
    const float inv = 1.0f / ((nrm > 1e-10f) ? nrm : 1.0f);
#pragma unroll
    for (int b = 0; b < NB; ++b)
        out[(size_t)b * length + p] = acc[b] * inv;
}

extern "C" void kernel_launch(void* const* d_in, const int* in_sizes, int n_in,
                              void* d_out, int out_size, void* d_ws, size_t ws_size,
                              hipStream_t stream) {
    // Static CQT geometry (host, deterministic). Matches np.round (banker's).
    CqtArgs a;
    const double SR = 44100.0;
    const double Q  = 1.0 / (std::exp2(1.0 / 12.0) - 1.0);
    int sum = 0;
    for (int k = 0; k < NBINS; ++k) {
        double f = 32.7 * std::exp2((double)k / 12.0);
        int L = (int)std::nearbyint(Q * SR / f);
        a.wl[k]    = L;
        a.off[k]   = sum;
        a.omega[k] = (float)(2.0 * 3.14159265358979323846 * f / SR);
        a.invL[k]  = (float)(1.0 / (double)L);
        sum += L;
    }
    const int maxL   = a.wl[0];
    const int length = out_size / NB;   // (256-1)*1024 + maxL = 283800
    const float* X = (const float*)d_in[0];
    float* out     = (float*)d_out;

    // ws layout: [ basis: sum half2 entries + 1024-entry over-read pad ][ Xt: 21504*8 float2 ]
    const size_t basisBytes = (size_t)sum * sizeof(__half2);
    const size_t xtOff      = (basisBytes + 1024 * sizeof(__half2) + 255) & ~(size_t)255;
    const size_t need       = xtOff + (size_t)NBINS * NFRAMES * NB * sizeof(float2);

    const int threads = 256;

    if (ws_size >= need) {
        __half2* basis = (__half2*)d_ws;
        float2*  Xt2   = (float2*)((char*)d_ws + xtOff);

        dim3 bb(NBINS, (maxL + threads - 1) / threads);
        build_basis_h2<<<bb, threads, 0, stream>>>(basis, a);

        const int ntr = NBINS * NFRAMES * NB;
        transpose_x<<<(ntr + threads - 1) / threads, threads, 0, stream>>>(
            (const float2*)X, Xt2);

        const int blocksPerHalf = (length + threads - 1) / threads;
        icqt_gather2<<<2 * blocksPerHalf, threads, 0, stream>>>(
            (const float4*)Xt2, out, basis, a, length, blocksPerHalf);
    } else {
        const int blocks = (length + threads - 1) / threads;
        icqt_gather_fallback<<<blocks, threads, 0, stream>>>(X, out, a, length);
    }
}

// Round 3
// 110.511 us; speedup vs baseline: 4.2151x; 1.7773x over previous
//
#include <hip/hip_runtime.h>
#include <cmath>

#define NBINS   84
#define NFRAMES 256
#define HOP     1024
#define NB      8     // nb_samples * nb_channels = 4*2

struct CqtArgs {
    int   wl[NBINS];     // per-bin window length (ragged)
    int   off[NBINS];    // prefix-sum offsets into basis table
    float omega[NBINS];  // radians per sample: 2*pi*f/SR
    float invL[NBINS];   // 1.0 / wl
};

// basis[off_k + t] = float2(cos(w t)*win, sin(w t)*win); win^2 = x^2 + y^2
__global__ void build_basis_f2(float2* __restrict__ basis, CqtArgs a) {
    const int k = blockIdx.x;
    const int L = a.wl[k];
    const int t = blockIdx.y * blockDim.x + threadIdx.x;
    if (t >= L) return;
    const float TWOPI = 6.28318530717958647692f;
    const float tf  = (float)t;
    const float ang = a.omega[k] * tf;
    const float w   = 0.5f - 0.5f * cosf(TWOPI * tf * a.invL[k]);
    basis[a.off[k] + t] = make_float2(cosf(ang) * w, sinf(ang) * w);
}

// Xt[(k*256+f)*8 + b] = X[b*(84*256) + k*256 + f]   (complex float2 entries)
__global__ void transpose_x(const float2* __restrict__ X2, float2* __restrict__ Xt2) {
    const int gid = blockIdx.x * blockDim.x + threadIdx.x;
    if (gid >= NBINS * NFRAMES * NB) return;
    Xt2[gid] = X2[(gid & 7) * (NBINS * NFRAMES) + (gid >> 3)];
}

// One thread per output position p; bins k = blockIdx.y, +nsplit, ...
// All 8 batches per thread (uniform Xt address -> compiler scalarizes to s_load).
// DIRECT: nsplit==1, divide by norm and write output. Else write 9 partial planes.
template<bool DIRECT>
__global__ __launch_bounds__(256)
void icqt_gather8(const float4* __restrict__ Xt4, float* __restrict__ dst,
                  const float2* __restrict__ basis, CqtArgs a,
                  int length, int nsplit) {
    const int p = blockIdx.x * blockDim.x + threadIdx.x;
    const int s = blockIdx.y;
    if (p >= length) return;

    float acc[NB];
#pragma unroll
    for (int b = 0; b < NB; ++b) acc[b] = 0.f;
    float nrm = 0.f;

    int fhi = p >> 10;                 // wave-uniform (64 | 1024)
    if (fhi > NFRAMES - 1) fhi = NFRAMES - 1;

    for (int k = s; k < NBINS; k += nsplit) {
        const int L   = a.wl[k];
        const int off = a.off[k];
        int flo = (p - L + HOP) >> 10;                 // per-lane; arith shift floors
        flo = __builtin_amdgcn_readfirstlane(flo);     // lane0 = min p = min flo
        if (flo < 0) flo = 0;
        if (flo > fhi) continue;                        // whole wave empty for bin k

        const float4* xp = Xt4 + ((size_t)(k * NFRAMES + flo) << 2);
        int t = p - (flo << 10);                        // >= 0 always

        // Peeled first frame: the only iteration where t >= L is possible.
        {
            const bool valid = (t < L);
            float2 bf = basis[off + t];                 // over-read <=63 entries: padded
            const float bre = valid ? bf.x : 0.f;
            const float bim = valid ? bf.y : 0.f;
            const float4 q0 = xp[0], q1 = xp[1], q2 = xp[2], q3 = xp[3];
            acc[0] += q0.x * bre - q0.y * bim;
            acc[1] += q0.z * bre - q0.w * bim;
            acc[2] += q1.x * bre - q1.y * bim;
            acc[3] += q1.z * bre - q1.w * bim;
            acc[4] += q2.x * bre - q2.y * bim;
            acc[5] += q2.z * bre - q2.w * bim;
            acc[6] += q3.x * bre - q3.y * bim;
            acc[7] += q3.z * bre - q3.w * bim;
            nrm += bre * bre + bim * bim;
            xp += 4; t -= HOP;
        }
        // Clean loop: every lane provably valid (0 <= t < L), no select needed.
        for (int f = flo + 1; f <= fhi; ++f, xp += 4, t -= HOP) {
            float2 bf = basis[off + t];
            const float bre = bf.x, bim = bf.y;
            const float4 q0 = xp[0], q1 = xp[1], q2 = xp[2], q3 = xp[3];
            acc[0] += q0.x * bre - q0.y * bim;
            acc[1] += q0.z * bre - q0.w * bim;
            acc[2] += q1.x * bre - q1.y * bim;
            acc[3] += q1.z * bre - q1.w * bim;
            acc[4] += q2.x * bre - q2.y * bim;
            acc[5] += q2.z * bre - q2.w * bim;
            acc[6] += q3.x * bre - q3.y * bim;
            acc[7] += q3.z * bre - q3.w * bim;
            nrm += bre * bre + bim * bim;
        }
    }

    if (DIRECT) {
        const float inv = 1.0f / ((nrm > 1e-10f) ? nrm : 1.0f);
#pragma unroll
        for (int b = 0; b < NB; ++b)
            dst[(size_t)b * length + p] = acc[b] * inv;
    } else {
        float* pp = dst + (size_t)s * 9 * length + p;
#pragma unroll
        for (int b = 0; b < NB; ++b)
            pp[(size_t)b * length] = acc[b];
        pp[(size_t)8 * length] = nrm;
    }
}

template<int S>
__global__ void reduce_out(const float* __restrict__ part, float* __restrict__ out,
                           int length) {
    const int p = blockIdx.x * blockDim.x + threadIdx.x;
    if (p >= length) return;
    float nrm = 0.f;
#pragma unroll
    for (int s = 0; s < S; ++s) nrm += part[((size_t)s * 9 + 8) * length + p];
    const float inv = 1.0f / ((nrm > 1e-10f) ? nrm : 1.0f);
#pragma unroll
    for (int b = 0; b < NB; ++b) {
        float v = 0.f;
#pragma unroll
        for (int s = 0; s < S; ++s) v += part[((size_t)s * 9 + b) * length + p];
        out[(size_t)b * length + p] = v * inv;
    }
}

// Last-resort fallback (ws too small even for basis+Xt): on-the-fly trig.
__global__ void icqt_gather_fallback(const float* __restrict__ X, float* __restrict__ out,
                                     CqtArgs a, int length) {
    const int p = blockIdx.x * blockDim.x + threadIdx.x;
    if (p >= length) return;
    float acc[NB];
#pragma unroll
    for (int b = 0; b < NB; ++b) acc[b] = 0.0f;
    float nrm = 0.0f;
    int fhi = p >> 10;
    if (fhi > NFRAMES - 1) fhi = NFRAMES - 1;
    const float2* X2 = reinterpret_cast<const float2*>(X);
    for (int k = 0; k < NBINS; ++k) {
        const int L = a.wl[k];
        int flo = (p - L + HOP) >> 10;
        if (flo < 0) flo = 0;
        for (int f = flo; f <= fhi; ++f) {
            const int t = p - (f << 10);
            if (t < L) {
                float tf = (float)t;
                float ang = a.omega[k] * tf;
                float s = sinf(ang), c = cosf(ang);
                float w = 0.5f - 0.5f * cosf(6.28318530717958647692f * tf * a.invL[k]);
                float bre = c * w, bim = s * w;
                nrm += w * w;
                const int base = k * NFRAMES + f;
#pragma unroll
                for (int b = 0; b < NB; ++b) {
                    float2 cv = X2[(size_t)b * (NBINS * NFRAMES) + base];
                    acc[b] += cv.x * bre - cv.y * bim;
                }
            }
        }
    }
    const float inv = 1.0f / ((nrm > 1e-10f) ? nrm : 1.0f);
#pragma unroll
    for (int b = 0; b < NB; ++b)
        out[(size_t)b * length + p] = acc[b] * inv;
}

extern "C" void kernel_launch(void* const* d_in, const int* in_sizes, int n_in,
                              void* d_out, int out_size, void* d_ws, size_t ws_size,
                              hipStream_t stream) {
    // Static CQT geometry (host, deterministic). Matches np.round (banker's).
    CqtArgs a;
    const double SR = 44100.0;
    const double Q  = 1.0 / (std::exp2(1.0 / 12.0) - 1.0);
    int sum = 0;
    for (int k = 0; k < NBINS; ++k) {
        double f = 32.7 * std::exp2((double)k / 12.0);
        int L = (int)std::nearbyint(Q * SR / f);
        a.wl[k]    = L;
        a.off[k]   = sum;
        a.omega[k] = (float)(2.0 * 3.14159265358979323846 * f / SR);
        a.invL[k]  = (float)(1.0 / (double)L);
        sum += L;
    }
    const int maxL   = a.wl[0];
    const int length = out_size / NB;   // (256-1)*1024 + maxL = 283800
    const float* X = (const float*)d_in[0];
    float* out     = (float*)d_out;

    const int threads = 256;
    const int bpg     = (length + threads - 1) / threads;   // blocks per split

    // ws layout: [ basis f2 + 1024-entry pad ][ Xt ][ partials S*9*length f32 ]
    const size_t basisBytes = (size_t)(sum + 1024) * sizeof(float2);
    const size_t xtOff   = (basisBytes + 255) & ~(size_t)255;
    const size_t xtBytes = (size_t)NBINS * NFRAMES * NB * sizeof(float2);
    const size_t partOff = (xtOff + xtBytes + 255) & ~(size_t)255;
    const size_t planeB  = (size_t)length * sizeof(float);

    const bool fit4    = ws_size >= partOff + 4 * 9 * planeB;
    const bool fit2    = ws_size >= partOff + 2 * 9 * planeB;
    const bool fitBase = ws_size >= partOff;

    if (!fitBase) {
        icqt_gather_fallback<<<bpg, threads, 0, stream>>>(X, out, a, length);
        return;
    }

    float2* basis = (float2*)d_ws;
    float2* Xt2   = (float2*)((char*)d_ws + xtOff);
    float*  part  = (float*)((char*)d_ws + partOff);

    dim3 bb(NBINS, (maxL + threads - 1) / threads);
    build_basis_f2<<<bb, threads, 0, stream>>>(basis, a);

    const int ntr = NBINS * NFRAMES * NB;
    transpose_x<<<(ntr + threads - 1) / threads, threads, 0, stream>>>(
        (const float2*)X, Xt2);

    if (fit4) {
        icqt_gather8<false><<<dim3(bpg, 4), threads, 0, stream>>>(
            (const float4*)Xt2, part, basis, a, length, 4);
        reduce_out<4><<<bpg, threads, 0, stream>>>(part, out, length);
    } else if (fit2) {
        icqt_gather8<false><<<dim3(bpg, 2), threads, 0, stream>>>(
            (const float4*)Xt2, part, basis, a, length, 2);
        reduce_out<2><<<bpg, threads, 0, stream>>>(part, out, length);
    } else {
        icqt_gather8<true><<<dim3(bpg, 1), threads, 0, stream>>>(
            (const float4*)Xt2, out, basis, a, length, 1);
    }
}